// Round 6
// baseline (252.308 us; speedup 1.0000x reference)
//
#include <hip/hip_runtime.h>
#include <hip/hip_bf16.h>

// Gram matrix: G = X @ X^T, X = [512, 65536] fp32, out = [512, 512] fp32.
// Round 16: per-CU load-interface model (from m13's 6.3 TB/s = ~10 B/cyc/CU):
// wall ~= vector-load bytes per CU / 10 B/cyc. r10: 640 MB issued / 256 CU
// = 2.5 MB/CU -> 104us predicted vs 100 measured. r15 same bytes -> same time.
// All r12-r15 rewrites kept bytes/CU constant -- that's why nothing moved.
// Only remaining lever: FEWER LOGICAL BYTES -> bigger tiles. 256^2 tiles cut
// logical traffic 537 -> 268 MB = 1.05 MB/CU -> ~44us + epilogue. r13 had
// this geometry but the gload_lds duty-cycle loop (126us). This round tests
// the unexplored cell: {256^2 tile x reg-staged float4 engine}:
//   - grid 256 x 1024 thr (16 waves, 4/SIMD = 2x r10's latency hiding),
//     1 block/CU; waves 4x4, each 64x64 out, acc[4][4] (r10's per-wave shape).
//   - explicit reg-prefetch: iter it+1's float4 loads issue right after the
//     stage-write, flying under frag-reads+MFMA (replaces the cross-block
//     overlap that 1 block/CU loses; r13's missing ingredient).
//   - every block: 16 iters, 64 KB fp32 staged/iter, ~1 MB interface bytes.
//     diag tiles: ONE panel [256][72] (no dup loads), BK=64, KC=1024, read
//     as both A and B operands; off tile: two [256][40] panels, BK=32, KC=512.
//   - diag blocks skip below-diagonal 64x64 sub-tile atomics (wn<wm);
//     mirror fills at 64-grain. Atomics 13.6M (+~10us vs r10, r6 scaling).
// History: r1 1.07GB 135us; r10 100; r11 100; r12 117(R); r13 126(R);
// r14 131(R); r15 109 (FETCH 262MB: chunk-major LLC thrash).

typedef short bf16x8 __attribute__((ext_vector_type(8)));   // 8 bf16 = 4 VGPRs
typedef float f32x4  __attribute__((ext_vector_type(4)));   // MFMA acc

#define HW    65536
#define CDIM  512
#define LDSO  40        // off-diag panel stride in shorts (r10 proven)
#define LDSD  72        // diag panel stride in shorts (64 + 8 pad)

__device__ __forceinline__ short f2bf(float f) {
    __hip_bfloat16 h = __float2bfloat16(f);   // RNE
    short s;
    __builtin_memcpy(&s, &h, sizeof(short));
    return s;
}

__device__ __forceinline__ bf16x8 cvt8(float4 a, float4 b) {
    bf16x8 v;
    v[0] = f2bf(a.x); v[1] = f2bf(a.y); v[2] = f2bf(a.z); v[3] = f2bf(a.w);
    v[4] = f2bf(b.x); v[5] = f2bf(b.y); v[6] = f2bf(b.z); v[7] = f2bf(b.w);
    return v;
}

__global__ __launch_bounds__(1024, 1)
void gram_kernel(const float* __restrict__ X, float* __restrict__ out) {
    // decode: p<128  -> diag tile ti=tj=p>>6 (256-grain), chunk=p&63,
    //                   KC=1024, BK=64, 16 iters, ONE panel.
    //         p>=128 -> off tile (0,1), chunk=p-128 (0..127),
    //                   KC=512, BK=32, 16 iters, TWO panels.
    // Every block stages 64 KB fp32 per iter -> uniform ~1 MB interface bytes.
    const int p = blockIdx.x;
    const bool diag = (p < 128);
    const int ti = diag ? (p >> 6) : 0;
    const int tj = diag ? ti : 1;
    const int kbase = diag ? ((p & 63) << 10) : ((p - 128) << 9);

    // LDS union: off = two [256][40] panels (40960 shorts);
    //            diag = one [256][72] panel (18432 shorts) aliased on top.
    __shared__ short LB[2 * 256 * LDSO];

    const int t    = threadIdx.x;        // 0..1023
    const int wave = t >> 6;             // 0..15
    const int lane = t & 63;
    const int wm   = wave & 3;           // 4x4 wave grid, each wave = 64x64
    const int wn   = wave >> 2;
    const int fm   = lane & 15;
    const int kg   = lane >> 4;          // 8 contiguous k per group

    f32x4 acc[4][4];
#pragma unroll
    for (int i = 0; i < 4; ++i)
#pragma unroll
        for (int j = 0; j < 4; ++j)
            acc[i][j] = (f32x4){0.f, 0.f, 0.f, 0.f};

    if (diag) {
        // ------------- diag: one panel [256][LDSD], BK=64 -------------
        const int srow = t >> 2;                 // 0..255 (4 threads/row)
        const int sq   = (t & 3) * 16;           // 16 consecutive floats
        const float* pd = X + (size_t)(ti * 256 + srow) * HW + kbase + sq;
        short* wd = LB + srow * LDSD + sq;

        int aoff[4], boff[4];
#pragma unroll
        for (int i = 0; i < 4; ++i) {
            aoff[i] = (wm * 64 + i * 16 + fm) * LDSD + kg * 8;
            boff[i] = (wn * 64 + i * 16 + fm) * LDSD + kg * 8;
        }

        float4 r0, r1, r2, r3;
#define LD_D do { r0 = *(const float4*)(pd + 0); r1 = *(const float4*)(pd + 4); \
                  r2 = *(const float4*)(pd + 8); r3 = *(const float4*)(pd + 12); } while (0)
        LD_D;
        for (int it = 0; it < 16; ++it) {
            bf16x8 v0 = cvt8(r0, r1), v1 = cvt8(r2, r3);
            __syncthreads();                     // prior LDS reads complete
            *(bf16x8*)(wd + 0) = v0;
            *(bf16x8*)(wd + 8) = v1;
            __syncthreads();                     // stage visible
            if (it < 15) { pd += 64; LD_D; }     // prefetch flies under MFMA

#pragma unroll
            for (int kk = 0; kk < 2; ++kk) {
                bf16x8 af[4], bfr[4];
#pragma unroll
                for (int i = 0; i < 4; ++i)
                    af[i]  = *(const bf16x8*)(LB + aoff[i] + kk * 32);
#pragma unroll
                for (int j = 0; j < 4; ++j)
                    bfr[j] = *(const bf16x8*)(LB + boff[j] + kk * 32);
#pragma unroll
                for (int i = 0; i < 4; ++i)
#pragma unroll
                    for (int j = 0; j < 4; ++j)
                        acc[i][j] = __builtin_amdgcn_mfma_f32_16x16x32_bf16(
                            af[i], bfr[j], acc[i][j], 0, 0, 0);
            }
        }
#undef LD_D
    } else {
        // ------------- off-diag: two panels [256][LDSO], BK=32 -------------
        const int srow = t >> 2;                 // 0..255 (4 threads/row)
        const int sq   = (t & 3) * 8;            // 8 consecutive floats
        const float* pa = X + (size_t)(ti * 256 + srow) * HW + kbase + sq;
        const float* pb = X + (size_t)(tj * 256 + srow) * HW + kbase + sq;
        short* wa = LB + srow * LDSO + sq;
        short* wb = LB + 256 * LDSO + srow * LDSO + sq;

        int aoff[4], boff[4];
#pragma unroll
        for (int i = 0; i < 4; ++i) {
            aoff[i] = (wm * 64 + i * 16 + fm) * LDSO + kg * 8;
            boff[i] = 256 * LDSO + (wn * 64 + i * 16 + fm) * LDSO + kg * 8;
        }

        float4 ra0, ra1, rb0, rb1;
#define LD_O do { ra0 = *(const float4*)(pa + 0); ra1 = *(const float4*)(pa + 4); \
                  rb0 = *(const float4*)(pb + 0); rb1 = *(const float4*)(pb + 4); } while (0)
        LD_O;
        for (int it = 0; it < 16; ++it) {
            bf16x8 va = cvt8(ra0, ra1), vb = cvt8(rb0, rb1);
            __syncthreads();                     // prior LDS reads complete
            *(bf16x8*)wa = va;
            *(bf16x8*)wb = vb;
            __syncthreads();                     // stage visible
            if (it < 15) { pa += 32; pb += 32; LD_O; }

            bf16x8 af[4], bfr[4];
#pragma unroll
            for (int i = 0; i < 4; ++i) af[i]  = *(const bf16x8*)(LB + aoff[i]);
#pragma unroll
            for (int j = 0; j < 4; ++j) bfr[j] = *(const bf16x8*)(LB + boff[j]);

#pragma unroll
            for (int i = 0; i < 4; ++i)
#pragma unroll
                for (int j = 0; j < 4; ++j)
                    acc[i][j] = __builtin_amdgcn_mfma_f32_16x16x32_bf16(
                        af[i], bfr[j], acc[i][j], 0, 0, 0);
        }
#undef LD_O
    }

    // --- epilogue: row-major coalesced atomics; diag skips lower sub-tiles ---
    // C/D layout (verified m89/m91): col = lane&15, row = (lane>>4)*4 + reg
    if (!diag || wn >= wm) {
        const int orow0 = ti * 256 + wm * 64 + (lane >> 4) * 4;
        const int ocol0 = tj * 256 + wn * 64 + fm;
#pragma unroll
        for (int i = 0; i < 4; ++i)
#pragma unroll
            for (int j = 0; j < 4; ++j)
#pragma unroll
                for (int r = 0; r < 4; ++r)
                    atomicAdd(out + (orow0 + i * 16 + r) * CDIM + ocol0 + j * 16,
                              acc[i][j][r]);
    }
}

// ---------------- mirror: copy upper 64-blocks transposed into lower ----------------
__global__ __launch_bounds__(256)
void mirror_kernel(float* __restrict__ out) {
    const int id = blockIdx.x * 256 + threadIdx.x;   // 0..262143
    const int r = id >> 9;
    const int c = id & 511;
    if ((r >> 6) > (c >> 6))          // 64-grain now (diag blocks skip wn<wm)
        out[id] = out[c * CDIM + r];
}

extern "C" void kernel_launch(void* const* d_in, const int* in_sizes, int n_in,
                              void* d_out, int out_size, void* d_ws, size_t ws_size,
                              hipStream_t stream) {
    const float* x = (const float*)d_in[0];
    float* out = (float*)d_out;

    // zero the accumulator (harness poisons d_out with 0xAA before every launch)
    hipMemsetAsync(d_out, 0, (size_t)out_size * sizeof(float), stream);

    gram_kernel<<<dim3(256), dim3(1024), 0, stream>>>(x, out);
    mirror_kernel<<<dim3(1024), dim3(256), 0, stream>>>(out);
}

// Round 7
// 236.406 us; speedup vs baseline: 1.0673x; 1.0673x over previous
//
#include <hip/hip_runtime.h>
#include <hip/hip_bf16.h>

// Gram matrix: G = X @ X^T, X = [512, 65536] fp32, out = [512, 512] fp32.
// Round 17: six structural rewrites (r12-r16) all lost to r10's plain loop.
// Surviving model: gram dur ~= issued vector-load bytes / (256 CU x 9-10
// B/cyc/CU). Measured: r1 12.9 B/cyc (best), r10 8.8, r15 10.0, r16 3.9.
// Only remaining lever: issue fewer bytes WITHOUT touching r10's engine.
// r10's one pocket of waste: diag blocks issued 1 MB each via 64 iters of
// half-MLP loads (the straggler pole). This round changes ONLY the decode:
//   - diag tiles: 64 chunks x KC=1024, 32 iters (was 32 x KC=2048, 64 it).
//     Same code path as upper (if(!diag) skips B); every block runs the
//     identical 32-iter schedule; diag blocks issue 0.5 MB and finish early
//     into the backfill queue. Issued 537 -> 512 MB. Grid 512 -> 640.
//   - upper (long) blocks launched first; tile-major order (r10's, FETCH 185
//     not r15's chunk-major 262 MB thrash).
//   - staging map, LDSS=40, inner loop, atomics epilogue, mirror: r10 exact.
// Pre-committed: if gram >= 95us, interface model confirmed at its ceiling
// -> declare roofline next round.
// History: r1 1.07GB 135us (12.9 B/cyc); r10 100; r11 100; r12 117(R);
// r13 126(R); r14 131(R); r15 109(R); r16 112(R).

typedef short bf16x8 __attribute__((ext_vector_type(8)));   // 8 bf16 = 4 VGPRs
typedef float f32x4  __attribute__((ext_vector_type(4)));   // MFMA acc

#define HW    65536
#define CDIM  512
#define LDSS  40        // panel stride in shorts (r10 proven)

__device__ __forceinline__ short f2bf(float f) {
    __hip_bfloat16 h = __float2bfloat16(f);   // RNE
    short s;
    __builtin_memcpy(&s, &h, sizeof(short));
    return s;
}

__device__ __forceinline__ bf16x8 cvt8(float4 a, float4 b) {
    bf16x8 v;
    v[0] = f2bf(a.x); v[1] = f2bf(a.y); v[2] = f2bf(a.z); v[3] = f2bf(a.w);
    v[4] = f2bf(b.x); v[5] = f2bf(b.y); v[6] = f2bf(b.z); v[7] = f2bf(b.w);
    return v;
}

__global__ __launch_bounds__(256, 2)
void gram_kernel(const float* __restrict__ X, float* __restrict__ out) {
    // decode (tile-major, upper tiles first -- they are the long blocks):
    //   p < 384  -> upper tile o = p>>6 (0..5), chunk = p&63
    //   p >= 384 -> diag tile (p-384)>>6 (0..3), chunk = (p-384)&63
    // ALL blocks: KC=1024, BK=32, 32 iterations, identical schedule;
    // diag blocks skip the B-panel loads (0.5 MB vs 1 MB issued).
    const int p = blockIdx.x;
    int ti, tj;
    if (p < 384) {
        const int o = p >> 6;
        const int TI[6] = {0, 0, 0, 1, 1, 2};
        const int TJ[6] = {1, 2, 3, 2, 3, 3};
        ti = TI[o]; tj = TJ[o];
    } else {
        ti = tj = (p - 384) >> 6;
    }
    const int kbase = (p & 63) << 10;
    const bool diag = (ti == tj);

    __shared__ short As[128 * LDSS];
    __shared__ short Bs[128 * LDSS];

    const int t    = threadIdx.x;
    const int wave = t >> 6;
    const int lane = t & 63;
    const int wm   = wave & 1;          // 2x2 wave grid, each wave = 64x64
    const int wn   = wave >> 1;

    // --- staging mapping (r10's): 2 threads per row, 16 consecutive fp32 ---
    const int srow  = t >> 1;           // 0..127
    const int shalf = (t & 1) * 16;     // k offset 0 or 16
    const float* pa = X + (size_t)(ti * 128 + srow) * HW + kbase + shalf;
    const float* pb = X + (size_t)(tj * 128 + srow) * HW + kbase + shalf;
    short* wa = As + srow * LDSS + shalf;
    short* wb = Bs + srow * LDSS + shalf;

    // --- fragment read offsets (A-operand: m = lane&15, k-group = lane>>4) ---
    const int fm = lane & 15;
    const int kg = lane >> 4;           // 0..3, each group = 8 contiguous k
    int a_off[4], b_off[4];
#pragma unroll
    for (int i = 0; i < 4; ++i) {
        a_off[i] = (wm * 64 + i * 16 + fm) * LDSS + kg * 8;
        b_off[i] = (wn * 64 + i * 16 + fm) * LDSS + kg * 8;
    }
    const short* Bbase = diag ? As : Bs;   // diag: B frags read the A panel

    f32x4 acc[4][4];
#pragma unroll
    for (int i = 0; i < 4; ++i)
#pragma unroll
        for (int j = 0; j < 4; ++j)
            acc[i][j] = (f32x4){0.f, 0.f, 0.f, 0.f};

    for (int it = 0; it < 32; ++it) {
        // global fp32 loads (16 floats per panel row-half; diag: A only)
        float4 a0 = *(const float4*)(pa + 0);
        float4 a1 = *(const float4*)(pa + 4);
        float4 a2 = *(const float4*)(pa + 8);
        float4 a3 = *(const float4*)(pa + 12);
        float4 b0, b1, b2, b3;
        if (!diag) {
            b0 = *(const float4*)(pb + 0);
            b1 = *(const float4*)(pb + 4);
            b2 = *(const float4*)(pb + 8);
            b3 = *(const float4*)(pb + 12);
        }

        bf16x8 va0 = cvt8(a0, a1), va1 = cvt8(a2, a3);
        bf16x8 vb0, vb1;
        if (!diag) { vb0 = cvt8(b0, b1); vb1 = cvt8(b2, b3); }

        __syncthreads();   // prior iteration's LDS reads complete
        *(bf16x8*)(wa + 0) = va0;
        *(bf16x8*)(wa + 8) = va1;
        if (!diag) {
            *(bf16x8*)(wb + 0) = vb0;
            *(bf16x8*)(wb + 8) = vb1;
        }
        __syncthreads();   // stage visible to all waves

        bf16x8 af[4], bfr[4];
#pragma unroll
        for (int i = 0; i < 4; ++i) af[i]  = *(const bf16x8*)(As + a_off[i]);
#pragma unroll
        for (int j = 0; j < 4; ++j) bfr[j] = *(const bf16x8*)(Bbase + b_off[j]);

#pragma unroll
        for (int i = 0; i < 4; ++i)
#pragma unroll
            for (int j = 0; j < 4; ++j)
                acc[i][j] = __builtin_amdgcn_mfma_f32_16x16x32_bf16(
                    af[i], bfr[j], acc[i][j], 0, 0, 0);

        pa += 32;
        pb += 32;
    }

    // --- epilogue: row-major coalesced atomics (diag/upper tiles only) ---
    // C/D layout (verified m89/m91): col = lane&15, row = (lane>>4)*4 + reg
    const int orow0 = ti * 128 + wm * 64 + (lane >> 4) * 4;
    const int ocol0 = tj * 128 + wn * 64 + fm;
#pragma unroll
    for (int i = 0; i < 4; ++i)
#pragma unroll
        for (int j = 0; j < 4; ++j)
#pragma unroll
            for (int r = 0; r < 4; ++r)
                atomicAdd(out + (orow0 + i * 16 + r) * CDIM + ocol0 + j * 16,
                          acc[i][j][r]);
}

// ---------------- mirror: copy upper tiles transposed into lower ----------------
__global__ __launch_bounds__(256)
void mirror_kernel(float* __restrict__ out) {
    const int id = blockIdx.x * 256 + threadIdx.x;   // 0..262143
    const int r = id >> 9;
    const int c = id & 511;
    if ((r >> 7) > (c >> 7))          // 128-grain tiles
        out[id] = out[c * CDIM + r];
}

extern "C" void kernel_launch(void* const* d_in, const int* in_sizes, int n_in,
                              void* d_out, int out_size, void* d_ws, size_t ws_size,
                              hipStream_t stream) {
    const float* x = (const float*)d_in[0];
    float* out = (float*)d_out;

    // zero the accumulator (harness poisons d_out with 0xAA before every launch)
    hipMemsetAsync(d_out, 0, (size_t)out_size * sizeof(float), stream);

    gram_kernel<<<dim3(640), dim3(256), 0, stream>>>(x, out);
    mirror_kernel<<<dim3(1024), dim3(256), 0, stream>>>(out);
}

// Round 8
// 227.888 us; speedup vs baseline: 1.1072x; 1.0374x over previous
//
#include <hip/hip_runtime.h>
#include <hip/hip_bf16.h>

// Gram matrix: G = X @ X^T, X = [512, 65536] fp32, out = [512, 512] fp32.
// Round 18: r17 disconfirmed the byte-interface model: gram time is nearly
// BYTE-INVARIANT (268-671 MB issued all land at 98-112us) -> a ~95us floor
// that byte reductions don't move. The one untested byte-invariant component
// shared by r10-r17: the ATOMIC epilogue -- 10.5M device-scope RMW adds into
// a 1 MB hot region (64 chunk-blocks per tile hammer the same lines; prior
// r6 measured ~17us per atomic doubling). This round changes ONLY that:
//   - gram blocks store their private 128x128 fp32 partial to d_ws
//     (640 x 64 KB = 41.9 MB contention-free streaming stores, same
//     coalescing pattern as the old atomics; slab = blockIdx).
//   - reduce_kernel (160 blocks): per tile element, sum the 64 chunk
//     partials (4-way float4 MLP, coalesced), write element + mirror.
//     This also ELIMINATES the d_out memset and the mirror kernel.
//   - staging engine, decode, LDS layout, MFMA loop: byte-for-byte r17.
//   - ws_size guard: falls back to r17's proven atomic path if d_ws < 42 MB.
// Pre-committed: if gram stays >=95us, the floor is structural -> declare
// effective roofline next round.
// History: r1 1.07GB 135us; r10 100; r11 100; r12 117(R); r13 126(R);
// r14 131(R); r15 109(R); r16 112(R); r17 98.3 (bench 236.4, best).

typedef short bf16x8 __attribute__((ext_vector_type(8)));   // 8 bf16 = 4 VGPRs
typedef float f32x4  __attribute__((ext_vector_type(4)));   // MFMA acc

#define HW    65536
#define CDIM  512
#define LDSS  40        // panel stride in shorts (r10 proven)
#define NBLK  640
#define TILE_ELEMS 16384   // 128*128

__device__ __forceinline__ short f2bf(float f) {
    __hip_bfloat16 h = __float2bfloat16(f);   // RNE
    short s;
    __builtin_memcpy(&s, &h, sizeof(short));
    return s;
}

__device__ __forceinline__ bf16x8 cvt8(float4 a, float4 b) {
    bf16x8 v;
    v[0] = f2bf(a.x); v[1] = f2bf(a.y); v[2] = f2bf(a.z); v[3] = f2bf(a.w);
    v[4] = f2bf(b.x); v[5] = f2bf(b.y); v[6] = f2bf(b.z); v[7] = f2bf(b.w);
    return v;
}

// USE_WS=1: store partial tile to workspace slab; USE_WS=0: r17 atomic path.
template <int USE_WS>
__global__ __launch_bounds__(256, 2)
void gram_kernel(const float* __restrict__ X, float* __restrict__ out,
                 float* __restrict__ ws) {
    // decode (tile-major, upper tiles first -- they are the long blocks):
    //   p < 384  -> upper tile o = p>>6 (0..5), chunk = p&63
    //   p >= 384 -> diag tile (p-384)>>6 (0..3), chunk = (p-384)&63
    // ALL blocks: KC=1024, BK=32, 32 iterations, identical schedule;
    // diag blocks skip the B-panel loads (0.5 MB vs 1 MB issued).
    const int p = blockIdx.x;
    int ti, tj;
    if (p < 384) {
        const int o = p >> 6;
        const int TI[6] = {0, 0, 0, 1, 1, 2};
        const int TJ[6] = {1, 2, 3, 2, 3, 3};
        ti = TI[o]; tj = TJ[o];
    } else {
        ti = tj = (p - 384) >> 6;
    }
    const int kbase = (p & 63) << 10;
    const bool diag = (ti == tj);

    __shared__ short As[128 * LDSS];
    __shared__ short Bs[128 * LDSS];

    const int t    = threadIdx.x;
    const int wave = t >> 6;
    const int lane = t & 63;
    const int wm   = wave & 1;          // 2x2 wave grid, each wave = 64x64
    const int wn   = wave >> 1;

    // --- staging mapping (r10's): 2 threads per row, 16 consecutive fp32 ---
    const int srow  = t >> 1;           // 0..127
    const int shalf = (t & 1) * 16;     // k offset 0 or 16
    const float* pa = X + (size_t)(ti * 128 + srow) * HW + kbase + shalf;
    const float* pb = X + (size_t)(tj * 128 + srow) * HW + kbase + shalf;
    short* wa = As + srow * LDSS + shalf;
    short* wb = Bs + srow * LDSS + shalf;

    // --- fragment read offsets (A-operand: m = lane&15, k-group = lane>>4) ---
    const int fm = lane & 15;
    const int kg = lane >> 4;           // 0..3, each group = 8 contiguous k
    int a_off[4], b_off[4];
#pragma unroll
    for (int i = 0; i < 4; ++i) {
        a_off[i] = (wm * 64 + i * 16 + fm) * LDSS + kg * 8;
        b_off[i] = (wn * 64 + i * 16 + fm) * LDSS + kg * 8;
    }
    const short* Bbase = diag ? As : Bs;   // diag: B frags read the A panel

    f32x4 acc[4][4];
#pragma unroll
    for (int i = 0; i < 4; ++i)
#pragma unroll
        for (int j = 0; j < 4; ++j)
            acc[i][j] = (f32x4){0.f, 0.f, 0.f, 0.f};

    for (int it = 0; it < 32; ++it) {
        // global fp32 loads (16 floats per panel row-half; diag: A only)
        float4 a0 = *(const float4*)(pa + 0);
        float4 a1 = *(const float4*)(pa + 4);
        float4 a2 = *(const float4*)(pa + 8);
        float4 a3 = *(const float4*)(pa + 12);
        float4 b0, b1, b2, b3;
        if (!diag) {
            b0 = *(const float4*)(pb + 0);
            b1 = *(const float4*)(pb + 4);
            b2 = *(const float4*)(pb + 8);
            b3 = *(const float4*)(pb + 12);
        }

        bf16x8 va0 = cvt8(a0, a1), va1 = cvt8(a2, a3);
        bf16x8 vb0, vb1;
        if (!diag) { vb0 = cvt8(b0, b1); vb1 = cvt8(b2, b3); }

        __syncthreads();   // prior iteration's LDS reads complete
        *(bf16x8*)(wa + 0) = va0;
        *(bf16x8*)(wa + 8) = va1;
        if (!diag) {
            *(bf16x8*)(wb + 0) = vb0;
            *(bf16x8*)(wb + 8) = vb1;
        }
        __syncthreads();   // stage visible to all waves

        bf16x8 af[4], bfr[4];
#pragma unroll
        for (int i = 0; i < 4; ++i) af[i]  = *(const bf16x8*)(As + a_off[i]);
#pragma unroll
        for (int j = 0; j < 4; ++j) bfr[j] = *(const bf16x8*)(Bbase + b_off[j]);

#pragma unroll
        for (int i = 0; i < 4; ++i)
#pragma unroll
            for (int j = 0; j < 4; ++j)
                acc[i][j] = __builtin_amdgcn_mfma_f32_16x16x32_bf16(
                    af[i], bfr[j], acc[i][j], 0, 0, 0);

        pa += 32;
        pb += 32;
    }

    // --- epilogue ---
    // C/D layout (verified m89/m91): col = lane&15, row = (lane>>4)*4 + reg
    if (USE_WS) {
        // contention-free streaming stores into this block's private slab
        float* slab = ws + (size_t)p * TILE_ELEMS;
        const int lrow0 = wm * 64 + (lane >> 4) * 4;
        const int lcol0 = wn * 64 + fm;
#pragma unroll
        for (int i = 0; i < 4; ++i)
#pragma unroll
            for (int j = 0; j < 4; ++j)
#pragma unroll
                for (int r = 0; r < 4; ++r)
                    slab[(lrow0 + i * 16 + r) * 128 + lcol0 + j * 16] =
                        acc[i][j][r];
    } else {
        const int orow0 = ti * 128 + wm * 64 + (lane >> 4) * 4;
        const int ocol0 = tj * 128 + wn * 64 + fm;
#pragma unroll
        for (int i = 0; i < 4; ++i)
#pragma unroll
            for (int j = 0; j < 4; ++j)
#pragma unroll
                for (int r = 0; r < 4; ++r)
                    atomicAdd(out + (orow0 + i * 16 + r) * CDIM + ocol0 + j * 16,
                              acc[i][j][r]);
    }
}

// ------- reduce: sum 64 chunk-partials per tile element, write out + mirror -------
// 40960 threads (160 blocks): thread handles 4 consecutive elements (float4)
// of one of the 10 unique tiles. Covers ALL of out (no memset, no mirror pass).
__global__ __launch_bounds__(256)
void reduce_kernel(const float* __restrict__ ws, float* __restrict__ out) {
    const int gid = blockIdx.x * 256 + threadIdx.x;    // 0..40959
    const int tt  = gid >> 12;                         // tile 0..9
    const int e4  = (gid & 4095) << 2;                 // element base 0..16380
    const int TI[10] = {0, 0, 0, 1, 1, 2, 0, 1, 2, 3};
    const int TJ[10] = {1, 2, 3, 2, 3, 3, 0, 1, 2, 3};
    const int ti = TI[tt], tj = TJ[tt];
    // slab layout follows gram decode: upper tiles at p=tt*64, diag at 384+
    const int slab0 = (tt < 6) ? (tt << 6) : (384 + ((tt - 6) << 6));
    const float* base = ws + (size_t)slab0 * TILE_ELEMS + e4;

    f32x4 s0 = {0.f, 0.f, 0.f, 0.f}, s1 = s0, s2 = s0, s3 = s0;
#pragma unroll
    for (int c = 0; c < 64; c += 4) {      // 4 independent chains (MLP)
        s0 += *(const f32x4*)(base + (size_t)(c + 0) * TILE_ELEMS);
        s1 += *(const f32x4*)(base + (size_t)(c + 1) * TILE_ELEMS);
        s2 += *(const f32x4*)(base + (size_t)(c + 2) * TILE_ELEMS);
        s3 += *(const f32x4*)(base + (size_t)(c + 3) * TILE_ELEMS);
    }
    const f32x4 s = (s0 + s1) + (s2 + s3);

    const int r0 = e4 >> 7;                // row in tile 0..127
    const int c0 = e4 & 127;               // col base in tile
    // main write (coalesced float4)
    *(f32x4*)(out + (ti * 128 + r0) * CDIM + tj * 128 + c0) = s;
    // mirror for upper tiles (transposed scalar stores)
    if (tt < 6) {
#pragma unroll
        for (int k = 0; k < 4; ++k)
            out[(tj * 128 + c0 + k) * CDIM + ti * 128 + r0] = s[k];
    }
}

// ---------------- fallback mirror (atomic path only) ----------------
__global__ __launch_bounds__(256)
void mirror_kernel(float* __restrict__ out) {
    const int id = blockIdx.x * 256 + threadIdx.x;   // 0..262143
    const int r = id >> 9;
    const int c = id & 511;
    if ((r >> 7) > (c >> 7))          // 128-grain tiles
        out[id] = out[c * CDIM + r];
}

extern "C" void kernel_launch(void* const* d_in, const int* in_sizes, int n_in,
                              void* d_out, int out_size, void* d_ws, size_t ws_size,
                              hipStream_t stream) {
    const float* x = (const float*)d_in[0];
    float* out = (float*)d_out;
    const size_t ws_needed = (size_t)NBLK * TILE_ELEMS * sizeof(float); // 41.9 MB

    if (d_ws != nullptr && ws_size >= ws_needed) {
        float* ws = (float*)d_ws;
        // no memset needed: reduce_kernel writes every out element exactly once
        gram_kernel<1><<<dim3(NBLK), dim3(256), 0, stream>>>(x, out, ws);
        reduce_kernel<<<dim3(160), dim3(256), 0, stream>>>(ws, out);
    } else {
        // fallback: r17's proven atomic path
        hipMemsetAsync(d_out, 0, (size_t)out_size * sizeof(float), stream);
        gram_kernel<0><<<dim3(NBLK), dim3(256), 0, stream>>>(x, out, nullptr);
        mirror_kernel<<<dim3(1024), dim3(256), 0, stream>>>(out);
    }
}